// Round 23
// baseline (104.329 us; speedup 1.0000x reference)
//
#include <hip/hip_runtime.h>

// ArcMarginLoss fused: normalize -> MX-fp4 MFMA GEMM + fixed-max softmax -> NLL mean.
// N=8192, D=512, C=32000, scale=16, margin=0.2.
// R23: LDS-broadcast B. R22 analysis: at 2 waves/SIMD the SIMD idles ~30% of
// issue slots (MfmaUtil+VALUBusy=69%); L2 BW no longer binding (13.7/34.5 TB/s).
// Fix: stage each 8KB B-chunk to LDS once per block (global_load_lds width=16,
// layout already linear 16B/lane), 4 waves share via conflict-free ds_read_b128.
// 1 A-tile/wave -> ~90 VGPR -> 4 waves/SIMD, 4 blocks/CU (grid 1024 exact),
// cross-block TLP hides the per-chunk barrier drain. L2 B-traffic 1.03GB->528MB.

typedef __attribute__((ext_vector_type(4))) float f32x4;
typedef __attribute__((ext_vector_type(16))) float f32x16;
typedef __attribute__((ext_vector_type(4))) int i32x4;
typedef __attribute__((ext_vector_type(8))) int i32x8;

constexpr int N = 8192, D = 512, C = 32000;
constexpr int BM = 128;            // rows per block (4 waves x 1 tile x 32 rows)
constexpr int NSPLIT = 16;         // column splits of C
constexpr int CPS = C / NSPLIT;    // 2000 real cols per split
constexpr int GCH = 63;            // padded chunks of 32 cols (2016) per split
constexpr int KS8 = 8;             // 8 k-steps of K=64
constexpr int XBLK = N / 4;        // 2048 prep blocks for x-norm+lab
constexpr float SCL = 16.0f;
constexpr float LOG2E = 1.4426950408889634f;
constexpr float S2 = SCL * LOG2E;              // folded into A pre-quant
constexpr float COSM = 0.98006657784124163f;  // cos(0.2)
constexpr float SINM = 0.19866933079506122f;  // sin(0.2)
constexpr float EPSC = 1e-7f;
constexpr float EM16 = 1.12535174719259114e-07f;  // exp(-16)
constexpr float FEC = 1064871712.0f;  // Schraudolph zero-mean magic (validated R12)

// fp4 e2m1 magnitude grid {0,.5,1,1.5,2,3,4,6} at codes 0..7.
__device__ __forceinline__ unsigned enc_fp4(float v, float inv) {
  unsigned s = (__float_as_uint(v) >> 31) << 3;
  float m = fabsf(v) * inv;
  float r = m < 2.0f ? 2.0f * m : (m < 4.0f ? m + 2.0f : fmaf(m, 0.5f, 4.0f));
  unsigned q = (unsigned)(r + 0.5f);
  return s | (q > 7u ? 7u : q);
}

// Per-32-block E8M0 scale from block absmax: smallest 2^e with absmax/2^e <= 6.
__device__ __forceinline__ void block_scale(float amax, unsigned& eB, float& inv) {
  unsigned u = __float_as_uint(amax * (1.0f / 6.0f));
  eB = (u >> 23) & 255u;
  if (u & 0x7fffffu) eB += 1u;      // ceil
  if (eB < 1u) eB = 1u;
  if (eB > 254u) eB = 254u;
  inv = __uint_as_float((254u - eB) << 23);  // 2^(127-eB)
}

__device__ __forceinline__ i32x8 up8(i32x4 v) {
  return __builtin_shufflevector(v, v, 0, 1, 2, 3, -1, -1, -1, -1);  // upper undef
}

__device__ __forceinline__ void gload_lds16(const void* g, void* l) {
  __builtin_amdgcn_global_load_lds(
      (const __attribute__((address_space(1))) void*)g,
      (__attribute__((address_space(3))) void*)l, 16, 0, 0);
}

// Fused prep: blocks [0,XBLK): x-norm (fp4 quant) + label-cosine (reuses x row
// registers). Blocks [XBLK, XBLK+16*GCH): w-norm into transposed fp4 chunk
// images + scale images (pad cols -> zeros).
__global__ void k_prep(const float* __restrict__ x, const float* __restrict__ w,
                       const int* __restrict__ labels,
                       unsigned* __restrict__ xn4, unsigned char* __restrict__ xsc,
                       unsigned char* __restrict__ wt4, unsigned char* __restrict__ wsc,
                       float* __restrict__ coslab, float* __restrict__ outz) {
  __shared__ unsigned lbuf[2048];         // 8KB chunk image (w path only)
  __shared__ unsigned char sbuf[512];     // scale image (w path only)
  const int tid = threadIdx.x, wv = tid >> 6, L = tid & 63;
  if (blockIdx.x == 0 && tid == 0) *outz = 0.0f;

  if (blockIdx.x < XBLK) {
    // ---- x-norm + lab: 4 rows per block, one wave per row ----
    int r = (blockIdx.x << 2) + wv;
    const float* row = x + (size_t)r * D;
    float f[8];
    *(f32x4*)&f[0] = *(const f32x4*)(row + L * 8);
    *(f32x4*)&f[4] = *(const f32x4*)(row + L * 8 + 4);
    float ss = 0.f;
    #pragma unroll
    for (int i = 0; i < 8; ++i) ss += f[i] * f[i];
    const float* wr = w + (size_t)labels[r] * D;
    float p[8];
    *(f32x4*)&p[0] = *(const f32x4*)(wr + L * 8);
    *(f32x4*)&p[4] = *(const f32x4*)(wr + L * 8 + 4);
    float ww = 0.f, xw = 0.f;
    #pragma unroll
    for (int i = 0; i < 8; ++i) { ww += p[i] * p[i]; xw += f[i] * p[i]; }
    #pragma unroll
    for (int m = 1; m <= 32; m <<= 1) {
      ss += __shfl_xor(ss, m, 64);
      ww += __shfl_xor(ww, m, 64);
      xw += __shfl_xor(xw, m, 64);
    }
    if (L == 0)
      coslab[r] = xw / (fmaxf(sqrtf(ss), 1e-12f) * fmaxf(sqrtf(ww), 1e-12f));
    float sc = S2 / fmaxf(sqrtf(ss), 1e-12f);
    float v[8], am = 0.f;
    #pragma unroll
    for (int i = 0; i < 8; ++i) { v[i] = f[i] * sc; am = fmaxf(am, fabsf(v[i])); }
    am = fmaxf(am, __shfl_xor(am, 1, 64));
    am = fmaxf(am, __shfl_xor(am, 2, 64));
    unsigned eB; float inv;
    block_scale(am, eB, inv);
    unsigned pk = 0;
    #pragma unroll
    for (int j = 0; j < 8; ++j) pk |= enc_fp4(v[j], inv) << (4 * j);
    xn4[(size_t)r * 64 + L] = pk;
    if ((L & 3) == 0) {
      int kb = L >> 2;  // k-block 0..15; kb = 2*ks + h
      xsc[(size_t)r * 16 + (kb & 1) * 8 + (kb >> 1)] = (unsigned char)eB;
    }
    return;
  }

  // ---- w-norm transpose: one block per padded 32-col chunk ----
  const int gidx = blockIdx.x - XBLK;
  const int sp = gidx / GCH, within = gidx % GCH;
  #pragma unroll
  for (int t = 0; t < 8; ++t) {
    int rl = t * 4 + wv;  // 0..31 (col within chunk)
    int colin = within * 32 + rl;
    bool valid = colin < CPS;             // wave-uniform
    unsigned pk = 0;
    unsigned eB = 1u;
    if (valid) {
      const float* row = w + ((size_t)sp * CPS + colin) * D;
      float f[8];
      *(f32x4*)&f[0] = *(const f32x4*)(row + L * 8);
      *(f32x4*)&f[4] = *(const f32x4*)(row + L * 8 + 4);
      float ss = 0.f;
      #pragma unroll
      for (int i = 0; i < 8; ++i) ss += f[i] * f[i];
      #pragma unroll
      for (int m = 1; m <= 32; m <<= 1) ss += __shfl_xor(ss, m, 64);
      float sc = 1.0f / fmaxf(sqrtf(ss), 1e-12f);
      float v[8], am = 0.f;
      #pragma unroll
      for (int i = 0; i < 8; ++i) { v[i] = f[i] * sc; am = fmaxf(am, fabsf(v[i])); }
      am = fmaxf(am, __shfl_xor(am, 1, 64));
      am = fmaxf(am, __shfl_xor(am, 2, 64));
      float inv;
      block_scale(am, eB, inv);
      #pragma unroll
      for (int j = 0; j < 8; ++j) pk |= enc_fp4(v[j], inv) << (4 * j);
    }
    // lane L covers k=8L..8L+8: ks=L>>3, h=(L>>2)&1, dword slot (L&3)
    lbuf[(L >> 3) * 256 + (((L >> 2) & 1) * 32 + rl) * 4 + (L & 3)] = pk;
    if ((L & 3) == 0) {
      int kb = L >> 2;
      sbuf[rl * 16 + (kb & 1) * 8 + (kb >> 1)] = (unsigned char)eB;
    }
  }
  __syncthreads();
  uint4* dst = (uint4*)(wt4 + (size_t)gidx * 8192);
  #pragma unroll
  for (int i = 0; i < 2; ++i) dst[i * 256 + tid] = ((const uint4*)lbuf)[i * 256 + tid];
  if (tid < 128)
    ((unsigned*)(wsc + (size_t)gidx * 512))[tid] = ((const unsigned*)sbuf)[tid];
}

// One k-step with LITERAL ks 0..7: ds_read_b128 of the shared B fragment
// (conflict-free: 64 lanes x 16B contiguous), one MFMA. ks=0 seeds from fzero.
#define KS_STEP(KSL)                                                          \
    {                                                                         \
      i32x4 b = *(const i32x4*)(lbase + (KSL) * 1024);                        \
      __builtin_amdgcn_s_setprio(1);                                          \
      acc = __builtin_amdgcn_mfma_scale_f32_32x32x64_f8f6f4(                  \
          up8(af4[KSL]), up8(b), (KSL) == 0 ? fzero : acc,                    \
          4, 4, (KSL) & 3, ((KSL) >> 2) ? ascB : ascA,                        \
                (KSL) & 3, ((KSL) >> 2) ? bscB : bscA);                       \
      __builtin_amdgcn_s_setprio(0);                                          \
    }

// Fused MX-fp4 32x32x64 GEMM: B staged to LDS once per block (4-wave share),
// double-buffered, one barrier per chunk; 4 waves/SIMD, 4 blocks/CU.
__global__ __launch_bounds__(256, 4) void k_fused(
    const unsigned char* __restrict__ xn4, const unsigned char* __restrict__ xsc,
    const unsigned char* __restrict__ wt4, const unsigned char* __restrict__ wsc,
    float* __restrict__ pS) {
  __shared__ __align__(16) unsigned char wbuf[2][8192];
  const int tid = threadIdx.x;
  const int wv = tid >> 6, lane = tid & 63;
  const int h = lane >> 5, c = lane & 31;
  const int bid = blockIdx.x;
  const int logical = (bid & 7) * 128 + (bid >> 3);  // 1024 = 8*128 XCD swizzle
  const int sp = logical >> 6;          // 0..15 (2 splits per XCD)
  const int rb = logical & 63;          // 0..63
  const int row0 = rb * BM + wv * 32;   // this wave's 32 rows (one 32x32 tile)

  // A-tile fully K-resident: af4[ks] = 16B at (row0+c)*256 + ks*32 + h*16.
  i32x4 af4[KS8];
  int ascA, ascB;
  {
    const unsigned char* xr = xn4 + (size_t)(row0 + c) * 256 + h * 16;
    #pragma unroll
    for (int ks = 0; ks < KS8; ++ks) af4[ks] = *(const i32x4*)(xr + ks * 32);
    ascA = *(const int*)(xsc + (size_t)(row0 + c) * 16 + h * 8);
    ascB = *(const int*)(xsc + (size_t)(row0 + c) * 16 + h * 8 + 4);
  }

  float accS[16];
  #pragma unroll
  for (int i = 0; i < 16; ++i) accS[i] = 0.0f;

  const f32x16 fzero = (f32x16)0.0f;

  // Staging: wave wv copies regions [2wv, 2wv+2) of the 8KB chunk image.
  const unsigned char* gstage = wt4 + (size_t)(sp * GCH) * 8192
                              + wv * 2048 + lane * 16;
  const unsigned char* gscn = wsc + (size_t)(sp * GCH) * 512 + c * 16 + h * 8;
  const unsigned char* lbase = &wbuf[0][0] + lane * 16;  // + cur*8192

  // Prologue: stage chunk 0 into buf 0.
  gload_lds16(gstage, &wbuf[0][0] + wv * 2048);
  gload_lds16(gstage + 1024, &wbuf[0][0] + wv * 2048 + 1024);
  int bscA = *(const int*)gscn;
  int bscB = *(const int*)(gscn + 4);
  gscn += 512;
  __syncthreads();

  f32x16 acc;
  int cur = 0;
  for (int ch = 0; ch < GCH; ++ch) {
    // Issue next chunk's stage into the other buffer (overlaps compute).
    if (ch + 1 < GCH) {
      const unsigned char* gs = gstage + (size_t)(ch + 1) * 8192;
      gload_lds16(gs, &wbuf[cur ^ 1][0] + wv * 2048);
      gload_lds16(gs + 1024, &wbuf[cur ^ 1][0] + wv * 2048 + 1024);
    }
    int nscA = *(const int*)gscn;
    int nscB = *(const int*)(gscn + 4);

    KS_STEP(0) KS_STEP(1) KS_STEP(2) KS_STEP(3)
    KS_STEP(4) KS_STEP(5) KS_STEP(6) KS_STEP(7)

    #pragma unroll
    for (int i = 0; i < 16; ++i)
      accS[i] += __uint_as_float((unsigned)fmaf(acc[i], 8388608.0f, FEC));

    bscA = nscA; bscB = nscB;
    gscn += 512;
    __syncthreads();   // stage of buf^1 complete; safe to swap
    cur ^= 1;
    lbase = &wbuf[cur][0] + lane * 16;
  }

  // Sum over the 32 col-lanes (within each half); write per-(row,split) partials.
  #pragma unroll
  for (int i = 0; i < 16; ++i) {
    float S = accS[i];
    #pragma unroll
    for (int m = 1; m <= 16; m <<= 1) S += __shfl_xor(S, m, 64);
    accS[i] = S;
  }
  if (c == 0) {
    #pragma unroll
    for (int i = 0; i < 16; ++i) {
      int rl = (i & 3) + 8 * (i >> 2) + 4 * h;  // verified 32x32 C/D row map
      pS[(size_t)sp * N + row0 + rl] = accS[i];
    }
  }
}
#undef KS_STEP

// Merge: S over splits; subtract exact pad contribution (256 cols x fastexp(0));
// x e^-16; swap plain label term for f32 margin term; NLL mean.
__global__ void k_merge(const float* __restrict__ pS, const float* __restrict__ coslab,
                        float* __restrict__ out) {
  int row = blockIdx.x * 256 + threadIdx.x;
  float S = 0.0f;
  #pragma unroll
  for (int s = 0; s < NSPLIT; ++s) S += pS[(size_t)s * N + row];
  S -= 256.0f * __uint_as_float((unsigned)FEC);  // exact pad-col correction
  float cl = coslab[row];
  float zp = SCL * cl;
  float ccl = fminf(fmaxf(cl, -1.0f + EPSC), 1.0f - EPSC);
  float zm = SCL * (ccl * COSM - sqrtf(1.0f - ccl * ccl) * SINM);
  float denom = S * EM16 - __expf(zp - SCL) + __expf(zm - SCL);
  float nll = SCL + logf(denom) - zm;
  #pragma unroll
  for (int m = 1; m <= 32; m <<= 1) nll += __shfl_xor(nll, m, 64);
  __shared__ float part[4];
  if ((threadIdx.x & 63) == 0) part[threadIdx.x >> 6] = nll;
  __syncthreads();
  if (threadIdx.x == 0)
    atomicAdd(out, (part[0] + part[1] + part[2] + part[3]) * (1.0f / N));
}

extern "C" void kernel_launch(void* const* d_in, const int* in_sizes, int n_in,
                              void* d_out, int out_size, void* d_ws, size_t ws_size,
                              hipStream_t stream) {
  const float* x = (const float*)d_in[0];
  const float* w = (const float*)d_in[1];
  const int* labels = (const int*)d_in[2];
  float* out = (float*)d_out;

  // ws: xn4 [N*256B] | xsc [N*16B] | wt4 [16*63*8KB] | wsc [16*63*512B]
  //   | pS f32 [NSPLIT*N] | coslab f32 [N]
  unsigned char* xn4 = (unsigned char*)d_ws;
  unsigned char* xsc = xn4 + (size_t)N * 256;
  unsigned char* wt4 = xsc + (size_t)N * 16;
  unsigned char* wsc = wt4 + (size_t)NSPLIT * GCH * 8192;
  float* pS = (float*)(wsc + (size_t)NSPLIT * GCH * 512);
  float* coslab = pS + (size_t)NSPLIT * N;

  hipLaunchKernelGGL(k_prep, dim3(XBLK + NSPLIT * GCH), dim3(256), 0, stream,
                     x, w, labels, (unsigned*)xn4, xsc, wt4, wsc, coslab, out);
  hipLaunchKernelGGL(k_fused, dim3(64 * NSPLIT), dim3(256), 0, stream,
                     xn4, xsc, wt4, wsc, pS);
  hipLaunchKernelGGL(k_merge, dim3(N / 256), dim3(256), 0, stream, pS, coslab, out);
}